// Round 7
// baseline (223.990 us; speedup 1.0000x reference)
//
#include <hip/hip_runtime.h>
#include <hip/hip_bf16.h>
#include <cstdint>

#define N_NODES 100000
#define HIDDEN  128
#define NEDGE   524288     // E; 2E = 8192 blocks x 128 edges
#define NT      6250       // 16-row wave-tiles per table (100000 = 16*6250)
#define PBLK    384        // precompute grid.x (768 blocks total = 3/CU)
#define WSTRIDE (PBLK * 2) // wave-tile stride (2 waves/block)

typedef __attribute__((ext_vector_type(8))) short short8;
typedef __attribute__((ext_vector_type(4))) float f32x4;

__device__ __forceinline__ unsigned short f2b(float f) {
    unsigned u = __float_as_uint(f);
    u += 0x7FFFu + ((u >> 16) & 1u);   // RNE; inputs finite
    return (unsigned short)(u >> 16);
}
__device__ __forceinline__ float b2f(unsigned x16) {
    return __uint_as_float(x16 << 16);
}

// async 16B/lane global->LDS. lds dest wave-uniform; HW adds lane*16.
__device__ __forceinline__ void async_copy16(const float* g, float* l) {
    __builtin_amdgcn_global_load_lds(
        (const __attribute__((address_space(1))) unsigned int*)g,
        (__attribute__((address_space(3))) unsigned int*)l,
        16, 0, 0);
}

// Pack W1 halves into MFMA A-fragment order (bf16):
// Wp[tb][f=n*4+ks][lane][8] = W1[tb*128 + ks*32 + q*8 + j][n*16 + t], lane=q*16+t
__global__ void wp_kernel(const float* __restrict__ W1,
                          unsigned short* __restrict__ Wp)
{
    const int f = blockIdx.x;        // 0..31
    const int tb = blockIdx.y;       // 0..1
    const int lane = threadIdx.x;    // 0..63
    const int t = lane & 15, q = lane >> 4;
    const int n = f >> 2, ks = f & 3;
    short8 v;
#pragma unroll
    for (int j = 0; j < 8; ++j)
        v[j] = (short)f2b(W1[(size_t)(tb * 128 + ks * 32 + q * 8 + j) * 128 + n * 16 + t]);
    *(short8*)(Wp + ((size_t)(tb * 32 + f) * 64 + lane) * 8) = v;
}

// A[m][n] = sum_k z[m][k] * W1half[k][n] (+ b1[n] for table 0), bf16 out.
// One wave per 16-row tile, grid-stride; W frags in 128 VGPRs.
// R7: TRIPLE-buffered global_load_lds staging, 2 tiles ahead, wait vmcnt(16).
// Safety (R6 post-mortem: stores retire out-of-order vs older loads, so
// vmcnt(12) raced): at each wait, exactly 16 LOADS were issued after the
// batch being consumed; outstanding<=16 => outstanding loads<=16 => loads
// retire in-order => remaining loads are within the two newest batches =>
// consumed batch fully in LDS, independent of store ack order. Loads get
// ~2 iterations of latency cover; stores ~2 iterations to ack.
// 2 waves/block, 48 KB LDS -> 3 blocks/CU, grid(384,2) all-resident.
__global__ __launch_bounds__(128, 2)
void precompute_kernel(const float* __restrict__ z_src,
                       const float* __restrict__ z_dst,
                       const unsigned short* __restrict__ Wp,
                       const float* __restrict__ b1,
                       unsigned short* __restrict__ Asrc,
                       unsigned short* __restrict__ Adst)
{
    const int table = blockIdx.y;
    const float* __restrict__ z = table ? z_dst : z_src;
    unsigned short* __restrict__ A = table ? Adst : Asrc;

    __shared__ float zbuf[2][3][2048];   // 48 KB: per-wave triple buffer

    const int tid = threadIdx.x;
    const int wave = tid >> 6;
    const int lane = tid & 63;
    const int t = lane & 15;
    const int q = lane >> 4;

    // W fragments -> registers (32 x short8 = 128 VGPR)
    short8 wfrag[32];
    {
        const unsigned short* wp = Wp + ((size_t)table * 32 * 64 + lane) * 8;
#pragma unroll
        for (int f = 0; f < 32; ++f)
            wfrag[f] = *(const short8*)(wp + (size_t)f * 64 * 8);
    }

    // b1 folded into table 0 (out col = n*16 + q*4 + r)
    float4 b1v[8];
#pragma unroll
    for (int n = 0; n < 8; ++n)
        b1v[n] = (table == 0) ? *(const float4*)(b1 + n * 16 + q * 4)
                              : make_float4(0.f, 0.f, 0.f, 0.f);

    const int lhi = lane >> 5;       // 0/1
    const int llo = lane & 31;
#define STAGE(m0, p)                                                          \
    do {                                                                      \
        _Pragma("unroll")                                                     \
        for (int j = 0; j < 8; ++j) {                                         \
            const int r = j * 2 + lhi;                                        \
            const int c = llo ^ (r & 7);                                      \
            async_copy16(z + (size_t)((m0) + r) * 128 + c * 4,                \
                         &zbuf[wave][p][j * 256]);                            \
        }                                                                     \
    } while (0)

    int tile = blockIdx.x * 2 + wave;    // 0..767; every wave has >=8 tiles
    STAGE(tile * 16, 0);                 // prologue: 2 tiles staged
    STAGE((tile + WSTRIDE) * 16, 1);
    __builtin_amdgcn_s_waitcnt(0xF70);   // vmcnt(0): prologue + wfrags resident
    asm volatile("" ::: "memory");

    int p = 0;
    while (tile < NT) {
        const int m0 = tile * 16;
        // stage tile+2*W into buffer (p+2)%3 (clamped: dummy reload at tail)
        const int t2 = tile + 2 * WSTRIDE;
        const int sm0 = (t2 < NT ? t2 : tile) * 16;
        int ps = p + 2; if (ps >= 3) ps -= 3;
        STAGE(sm0, ps);
        asm volatile("" ::: "memory");
        __builtin_amdgcn_s_waitcnt(0x4F70);  // vmcnt(16): consumed batch drained
        asm volatile("" ::: "memory");

        // fragment reads + fp32->bf16 convert (buffer p)
        short8 b[4];
#pragma unroll
        for (int ks = 0; ks < 4; ++ks) {
            const int c0 = ks * 8 + 2 * q;
            const int s = t & 7;
            const float4 v0 = *(const float4*)&zbuf[wave][p][(t * 32 + (c0 ^ s)) * 4];
            const float4 v1 = *(const float4*)&zbuf[wave][p][(t * 32 + ((c0 + 1) ^ s)) * 4];
            b[ks][0] = (short)f2b(v0.x); b[ks][1] = (short)f2b(v0.y);
            b[ks][2] = (short)f2b(v0.z); b[ks][3] = (short)f2b(v0.w);
            b[ks][4] = (short)f2b(v1.x); b[ks][5] = (short)f2b(v1.y);
            b[ks][6] = (short)f2b(v1.z); b[ks][7] = (short)f2b(v1.w);
        }

        f32x4 acc[8];
#pragma unroll
        for (int n = 0; n < 8; ++n) acc[n] = (f32x4){0.f, 0.f, 0.f, 0.f};
#pragma unroll
        for (int n = 0; n < 8; ++n)
#pragma unroll
            for (int ks = 0; ks < 4; ++ks)
                acc[n] = __builtin_amdgcn_mfma_f32_16x16x32_bf16(
                             wfrag[n * 4 + ks], b[ks], acc[n], 0, 0, 0);

        // epilogue: stage D in LDS buffer p (consumed; restaged only at next
        // iteration's STAGE, which issues after these reads complete), then
        // coalesced 16B/lane full-row stores. Row stride 136 ushort; 8B chunks
        // XOR-swizzled by row -> read-back 2-way (free).
        unsigned short* ob = (unsigned short*)&zbuf[wave][p][0];
        const int sw = (t & 7) * 2;
#pragma unroll
        for (int n = 0; n < 8; ++n) {
            ushort4 h;
            h.x = f2b(acc[n][0] + b1v[n].x);
            h.y = f2b(acc[n][1] + b1v[n].y);
            h.z = f2b(acc[n][2] + b1v[n].z);
            h.w = f2b(acc[n][3] + b1v[n].w);
            *(ushort4*)&ob[t * 136 + (((n * 4 + q) ^ sw) * 4)] = h;
        }
        const int rr = lane >> 4;            // 0..3
#pragma unroll
        for (int it = 0; it < 4; ++it) {
            const int r = it * 4 + rr;
            const uint4 v = *(const uint4*)&ob[r * 136 + (((2 * t) ^ ((r & 7) * 2)) * 4)];
            *(uint4*)(A + (size_t)(m0 + r) * 128 + t * 8) = v;
        }
        asm volatile("" ::: "memory");

        tile += WSTRIDE;
        ++p; if (p >= 3) p -= 3;
    }
#undef STAGE
}

// 16 lanes per edge; lane owns 8 hidden units (16B bf16 gather per table).
// out[e] = sum_j relu(Asrc'[s][j] + Adst[d][j]) * W2[j] + b2   (b1 folded in)
// R4 structure (measured best; occupancy-insensitive path ceiling).
__global__ __launch_bounds__(256, 4)
void edge_kernel(const unsigned short* __restrict__ Asrc,
                 const unsigned short* __restrict__ Adst,
                 const int* __restrict__ pos_src,
                 const int* __restrict__ pos_dst,
                 const int* __restrict__ neg_src,
                 const int* __restrict__ neg_dst,
                 const float* __restrict__ W2,
                 const float* __restrict__ b2,
                 float* __restrict__ out)
{
    const int tid = threadIdx.x;
    const int t = tid & 15;      // hidden slice t*8 .. t*8+7
    const int g = tid >> 4;      // edge group within block (0..15)

    const bool is_pos = blockIdx.x < 4096;
    const int* __restrict__ sp = is_pos ? pos_src : neg_src;
    const int* __restrict__ dp = is_pos ? pos_dst : neg_dst;
    const int eb = (is_pos ? (int)blockIdx.x : (int)blockIdx.x - 4096) * 128;

    float w2r[8];
#pragma unroll
    for (int j = 0; j < 8; ++j) w2r[j] = W2[t * 8 + j];
    const float bias2 = b2[0];

    int sidx[8], didx[8];
#pragma unroll
    for (int i = 0; i < 8; ++i) {
        sidx[i] = sp[eb + i * 16 + g];
        didx[i] = dp[eb + i * 16 + g];
    }

    uint4 ua[8], ub[8];
#pragma unroll
    for (int i = 0; i < 8; ++i) {
        ua[i] = *(const uint4*)(Asrc + (size_t)sidx[i] * 128 + t * 8);
        ub[i] = *(const uint4*)(Adst + (size_t)didx[i] * 128 + t * 8);
    }

#pragma unroll
    for (int i = 0; i < 8; ++i) {
        float acc = 0.f;
        const unsigned* pa = (const unsigned*)&ua[i];
        const unsigned* pb = (const unsigned*)&ub[i];
#pragma unroll
        for (int j2 = 0; j2 < 4; ++j2) {
            float h0 = b2f(pa[j2] & 0xFFFFu) + b2f(pb[j2] & 0xFFFFu);
            float h1 = b2f(pa[j2] >> 16)     + b2f(pb[j2] >> 16);
            h0 = fmaxf(h0, 0.f);
            h1 = fmaxf(h1, 0.f);
            acc = fmaf(h0, w2r[2 * j2], acc);
            acc = fmaf(h1, w2r[2 * j2 + 1], acc);
        }
        acc += __shfl_xor(acc, 1);
        acc += __shfl_xor(acc, 2);
        acc += __shfl_xor(acc, 4);
        acc += __shfl_xor(acc, 8);
        if (t == 0) out[blockIdx.x * 128 + i * 16 + g] = acc + bias2;
    }
}

extern "C" void kernel_launch(void* const* d_in, const int* in_sizes, int n_in,
                              void* d_out, int out_size, void* d_ws, size_t ws_size,
                              hipStream_t stream) {
    const float* z_src  = (const float*)d_in[0];
    const float* z_dst  = (const float*)d_in[1];
    const int* pos_src  = (const int*)d_in[2];
    const int* pos_dst  = (const int*)d_in[3];
    const int* neg_src  = (const int*)d_in[4];
    const int* neg_dst  = (const int*)d_in[5];
    const float* W1     = (const float*)d_in[6];
    const float* b1     = (const float*)d_in[7];
    const float* W2     = (const float*)d_in[8];
    const float* b2     = (const float*)d_in[9];
    float* out = (float*)d_out;

    unsigned short* Asrc = (unsigned short*)d_ws;                 // 25.6 MB
    unsigned short* Adst = Asrc + (size_t)N_NODES * HIDDEN;       // 25.6 MB
    unsigned short* Wp   = Adst + (size_t)N_NODES * HIDDEN;       // 64 KB

    wp_kernel<<<dim3(32, 2), 64, 0, stream>>>(W1, Wp);

    precompute_kernel<<<dim3(PBLK, 2), 128, 0, stream>>>(z_src, z_dst, Wp, b1,
                                                         Asrc, Adst);

    edge_kernel<<<8192, 256, 0, stream>>>(Asrc, Adst, pos_src, pos_dst,
                                          neg_src, neg_dst, W2, b2, out);
}

// Round 8
// 223.265 us; speedup vs baseline: 1.0032x; 1.0032x over previous
//
#include <hip/hip_runtime.h>
#include <hip/hip_bf16.h>
#include <cstdint>

#define N_NODES 100000
#define HIDDEN  128
#define NEDGE   524288     // E; 2E = 8192 blocks x 128 edges
#define NT      6250       // 16-row wave-tiles per table (100000 = 16*6250)
#define PBLK    256        // precompute grid.x (512 blocks total = 2/CU)
#define WSTRIDE (PBLK * 2) // wave-tile stride (2 waves/block)

typedef __attribute__((ext_vector_type(8))) short short8;
typedef __attribute__((ext_vector_type(4))) float f32x4;

__device__ __forceinline__ unsigned short f2b(float f) {
    unsigned u = __float_as_uint(f);
    u += 0x7FFFu + ((u >> 16) & 1u);   // RNE; inputs finite
    return (unsigned short)(u >> 16);
}
__device__ __forceinline__ float b2f(unsigned x16) {
    return __uint_as_float(x16 << 16);
}

// async 16B/lane global->LDS. lds dest wave-uniform; HW adds lane*16.
__device__ __forceinline__ void async_copy16(const float* g, float* l) {
    __builtin_amdgcn_global_load_lds(
        (const __attribute__((address_space(1))) unsigned int*)g,
        (__attribute__((address_space(3))) unsigned int*)l,
        16, 0, 0);
}

// Pack W1 halves into MFMA A-fragment order (bf16):
// Wp[tb][f=n*4+ks][lane][8] = W1[tb*128 + ks*32 + q*8 + j][n*16 + t], lane=q*16+t
__global__ void wp_kernel(const float* __restrict__ W1,
                          unsigned short* __restrict__ Wp)
{
    const int f = blockIdx.x;        // 0..31
    const int tb = blockIdx.y;       // 0..1
    const int lane = threadIdx.x;    // 0..63
    const int t = lane & 15, q = lane >> 4;
    const int n = f >> 2, ks = f & 3;
    short8 v;
#pragma unroll
    for (int j = 0; j < 8; ++j)
        v[j] = (short)f2b(W1[(size_t)(tb * 128 + ks * 32 + q * 8 + j) * 128 + n * 16 + t]);
    *(short8*)(Wp + ((size_t)(tb * 32 + f) * 64 + lane) * 8) = v;
}

// A[m][n] = sum_k z[m][k] * W1half[k][n] (+ b1[n] for table 0), bf16 out.
// One wave per 16-row tile, grid-stride; W frags in 128 VGPRs.
// R8: QUAD-buffered ring, stage 3 tiles ahead, wait vmcnt(24).
// Safety (stores retire OOO vs older loads — R6 lesson): at each wait,
// exactly 24 LOADS (3 batches) were issued after the batch being consumed;
// outstanding<=24 => outstanding loads<=24 => loads retire in-order =>
// remaining loads are within the 3 newest batches => consumed batch fully
// in LDS, independent of store ack order. Consumed batch now has ~3 rounds
// (~2400 cyc) of latency cover vs ~900-cyc HBM latency, and the 8 possible
// outstanding store-instrs have ~3 rounds to ack before gating the count
// (the R7 vmcnt(16) flaw). 2 waves/block, 64 KB LDS -> 2 blocks/CU.
__global__ __launch_bounds__(128, 2)
void precompute_kernel(const float* __restrict__ z_src,
                       const float* __restrict__ z_dst,
                       const unsigned short* __restrict__ Wp,
                       const float* __restrict__ b1,
                       unsigned short* __restrict__ Asrc,
                       unsigned short* __restrict__ Adst)
{
    const int table = blockIdx.y;
    const float* __restrict__ z = table ? z_dst : z_src;
    unsigned short* __restrict__ A = table ? Adst : Asrc;

    __shared__ float zbuf[2][4][2048];   // 64 KB: per-wave quad ring

    const int tid = threadIdx.x;
    const int wave = tid >> 6;
    const int lane = tid & 63;
    const int t = lane & 15;
    const int q = lane >> 4;

    // W fragments -> registers (32 x short8 = 128 VGPR)
    short8 wfrag[32];
    {
        const unsigned short* wp = Wp + ((size_t)table * 32 * 64 + lane) * 8;
#pragma unroll
        for (int f = 0; f < 32; ++f)
            wfrag[f] = *(const short8*)(wp + (size_t)f * 64 * 8);
    }

    // b1 folded into table 0 (out col = n*16 + q*4 + r)
    float4 b1v[8];
#pragma unroll
    for (int n = 0; n < 8; ++n)
        b1v[n] = (table == 0) ? *(const float4*)(b1 + n * 16 + q * 4)
                              : make_float4(0.f, 0.f, 0.f, 0.f);

    const int lhi = lane >> 5;       // 0/1
    const int llo = lane & 31;
#define STAGE(m0, p)                                                          \
    do {                                                                      \
        _Pragma("unroll")                                                     \
        for (int j = 0; j < 8; ++j) {                                         \
            const int r = j * 2 + lhi;                                        \
            const int c = llo ^ (r & 7);                                      \
            async_copy16(z + (size_t)((m0) + r) * 128 + c * 4,                \
                         &zbuf[wave][p][j * 256]);                            \
        }                                                                     \
    } while (0)

    int tile = blockIdx.x * 2 + wave;    // 0..511; every wave has >=12 tiles
    // prologue: 3 tiles staged (tile+2*WSTRIDE <= 1535 < NT always)
    STAGE(tile * 16, 0);
    STAGE((tile + WSTRIDE) * 16, 1);
    STAGE((tile + 2 * WSTRIDE) * 16, 2);
    __builtin_amdgcn_s_waitcnt(0xF70);   // vmcnt(0): prologue + wfrags resident
    asm volatile("" ::: "memory");

    int p = 0;
    while (tile < NT) {
        const int m0 = tile * 16;
        // stage tile+3*W into buffer (p+3)&3 (clamped: dummy reload at tail)
        const int t3 = tile + 3 * WSTRIDE;
        const int sm0 = (t3 < NT ? t3 : tile) * 16;
        STAGE(sm0, (p + 3) & 3);
        asm volatile("" ::: "memory");
        __builtin_amdgcn_s_waitcnt(0x4F78);  // vmcnt(24): consumed batch drained
        asm volatile("" ::: "memory");

        // fragment reads + fp32->bf16 convert (buffer p)
        short8 b[4];
#pragma unroll
        for (int ks = 0; ks < 4; ++ks) {
            const int c0 = ks * 8 + 2 * q;
            const int s = t & 7;
            const float4 v0 = *(const float4*)&zbuf[wave][p][(t * 32 + (c0 ^ s)) * 4];
            const float4 v1 = *(const float4*)&zbuf[wave][p][(t * 32 + ((c0 + 1) ^ s)) * 4];
            b[ks][0] = (short)f2b(v0.x); b[ks][1] = (short)f2b(v0.y);
            b[ks][2] = (short)f2b(v0.z); b[ks][3] = (short)f2b(v0.w);
            b[ks][4] = (short)f2b(v1.x); b[ks][5] = (short)f2b(v1.y);
            b[ks][6] = (short)f2b(v1.z); b[ks][7] = (short)f2b(v1.w);
        }

        f32x4 acc[8];
#pragma unroll
        for (int n = 0; n < 8; ++n) acc[n] = (f32x4){0.f, 0.f, 0.f, 0.f};
#pragma unroll
        for (int n = 0; n < 8; ++n)
#pragma unroll
            for (int ks = 0; ks < 4; ++ks)
                acc[n] = __builtin_amdgcn_mfma_f32_16x16x32_bf16(
                             wfrag[n * 4 + ks], b[ks], acc[n], 0, 0, 0);

        // epilogue: stage D in LDS buffer p (consumed; it is restaged only at
        // the NEXT iteration's STAGE, which issues after these reads' data is
        // consumed), then coalesced 16B/lane full-row stores. Row stride 136
        // ushort; 8B chunks XOR-swizzled by row -> read-back 2-way (free).
        unsigned short* ob = (unsigned short*)&zbuf[wave][p][0];
        const int sw = (t & 7) * 2;
#pragma unroll
        for (int n = 0; n < 8; ++n) {
            ushort4 h;
            h.x = f2b(acc[n][0] + b1v[n].x);
            h.y = f2b(acc[n][1] + b1v[n].y);
            h.z = f2b(acc[n][2] + b1v[n].z);
            h.w = f2b(acc[n][3] + b1v[n].w);
            *(ushort4*)&ob[t * 136 + (((n * 4 + q) ^ sw) * 4)] = h;
        }
        const int rr = lane >> 4;            // 0..3
#pragma unroll
        for (int it = 0; it < 4; ++it) {
            const int r = it * 4 + rr;
            const uint4 v = *(const uint4*)&ob[r * 136 + (((2 * t) ^ ((r & 7) * 2)) * 4)];
            *(uint4*)(A + (size_t)(m0 + r) * 128 + t * 8) = v;
        }
        asm volatile("" ::: "memory");

        tile += WSTRIDE;
        p = (p + 1) & 3;
    }
#undef STAGE
}

// 16 lanes per edge; lane owns 8 hidden units (16B bf16 gather per table).
// out[e] = sum_j relu(Asrc'[s][j] + Adst[d][j]) * W2[j] + b2   (b1 folded in)
// R4 structure (measured best; at random-256B DRAM-efficiency ceiling:
// 3.45-3.55 TB/s constant across occupancy 45-70% and access structures).
__global__ __launch_bounds__(256, 4)
void edge_kernel(const unsigned short* __restrict__ Asrc,
                 const unsigned short* __restrict__ Adst,
                 const int* __restrict__ pos_src,
                 const int* __restrict__ pos_dst,
                 const int* __restrict__ neg_src,
                 const int* __restrict__ neg_dst,
                 const float* __restrict__ W2,
                 const float* __restrict__ b2,
                 float* __restrict__ out)
{
    const int tid = threadIdx.x;
    const int t = tid & 15;      // hidden slice t*8 .. t*8+7
    const int g = tid >> 4;      // edge group within block (0..15)

    const bool is_pos = blockIdx.x < 4096;
    const int* __restrict__ sp = is_pos ? pos_src : neg_src;
    const int* __restrict__ dp = is_pos ? pos_dst : neg_dst;
    const int eb = (is_pos ? (int)blockIdx.x : (int)blockIdx.x - 4096) * 128;

    float w2r[8];
#pragma unroll
    for (int j = 0; j < 8; ++j) w2r[j] = W2[t * 8 + j];
    const float bias2 = b2[0];

    int sidx[8], didx[8];
#pragma unroll
    for (int i = 0; i < 8; ++i) {
        sidx[i] = sp[eb + i * 16 + g];
        didx[i] = dp[eb + i * 16 + g];
    }

    uint4 ua[8], ub[8];
#pragma unroll
    for (int i = 0; i < 8; ++i) {
        ua[i] = *(const uint4*)(Asrc + (size_t)sidx[i] * 128 + t * 8);
        ub[i] = *(const uint4*)(Adst + (size_t)didx[i] * 128 + t * 8);
    }

#pragma unroll
    for (int i = 0; i < 8; ++i) {
        float acc = 0.f;
        const unsigned* pa = (const unsigned*)&ua[i];
        const unsigned* pb = (const unsigned*)&ub[i];
#pragma unroll
        for (int j2 = 0; j2 < 4; ++j2) {
            float h0 = b2f(pa[j2] & 0xFFFFu) + b2f(pb[j2] & 0xFFFFu);
            float h1 = b2f(pa[j2] >> 16)     + b2f(pb[j2] >> 16);
            h0 = fmaxf(h0, 0.f);
            h1 = fmaxf(h1, 0.f);
            acc = fmaf(h0, w2r[2 * j2], acc);
            acc = fmaf(h1, w2r[2 * j2 + 1], acc);
        }
        acc += __shfl_xor(acc, 1);
        acc += __shfl_xor(acc, 2);
        acc += __shfl_xor(acc, 4);
        acc += __shfl_xor(acc, 8);
        if (t == 0) out[blockIdx.x * 128 + i * 16 + g] = acc + bias2;
    }
}

extern "C" void kernel_launch(void* const* d_in, const int* in_sizes, int n_in,
                              void* d_out, int out_size, void* d_ws, size_t ws_size,
                              hipStream_t stream) {
    const float* z_src  = (const float*)d_in[0];
    const float* z_dst  = (const float*)d_in[1];
    const int* pos_src  = (const int*)d_in[2];
    const int* pos_dst  = (const int*)d_in[3];
    const int* neg_src  = (const int*)d_in[4];
    const int* neg_dst  = (const int*)d_in[5];
    const float* W1     = (const float*)d_in[6];
    const float* b1     = (const float*)d_in[7];
    const float* W2     = (const float*)d_in[8];
    const float* b2     = (const float*)d_in[9];
    float* out = (float*)d_out;

    unsigned short* Asrc = (unsigned short*)d_ws;                 // 25.6 MB
    unsigned short* Adst = Asrc + (size_t)N_NODES * HIDDEN;       // 25.6 MB
    unsigned short* Wp   = Adst + (size_t)N_NODES * HIDDEN;       // 64 KB

    wp_kernel<<<dim3(32, 2), 64, 0, stream>>>(W1, Wp);

    precompute_kernel<<<dim3(PBLK, 2), 128, 0, stream>>>(z_src, z_dst, Wp, b1,
                                                         Asrc, Adst);

    edge_kernel<<<8192, 256, 0, stream>>>(Asrc, Adst, pos_src, pos_dst,
                                          neg_src, neg_dst, W2, b2, out);
}